// Round 1
// 1336.713 us; speedup vs baseline: 1.2008x; 1.2008x over previous
//
#include <hip/hip_runtime.h>

#define B_ 32
#define C_ 8
#define K_ 32

__device__ __forceinline__ float2 cmul(float2 a, float2 b) {
  return make_float2(a.x*b.x - a.y*b.y, a.x*b.y + a.y*b.x);
}
__device__ __forceinline__ float2 cmulc(float2 a, float2 b) { // a * conj(b)
  return make_float2(a.x*b.x + a.y*b.y, a.y*b.x - a.x*b.y);
}
__device__ __forceinline__ float2 cadd(float2 a, float2 b){ return make_float2(a.x+b.x, a.y+b.y); }
__device__ __forceinline__ float2 csub(float2 a, float2 b){ return make_float2(a.x-b.x, a.y-b.y); }
// 8-col-block skew: kills the tp*64B 8-way bank-conflict pattern while keeping
// float4 contiguity inside each octet (base SK(8*tp) = 10*tp, 16B-aligned).
__device__ __forceinline__ int SK(int r){ return r + ((r >> 3) << 1); }

__device__ void herm4_inv(float2 a[4][4], float2 out[4][4]) {
  float idg[4];
  for (int j = 0; j < 4; ++j) {
    float d = sqrtf(fmaxf(a[j][j].x, 1e-30f));
    float id = 1.f / d;
    idg[j] = id;
    a[j][j] = make_float2(d, 0.f);
    for (int r = j+1; r < 4; ++r) { a[r][j].x *= id; a[r][j].y *= id; }
    for (int c = j+1; c < 4; ++c)
      for (int r = c; r < 4; ++r)
        a[r][c] = csub(a[r][c], cmulc(a[r][j], a[c][j]));
  }
  float2 li[4][4];
  for (int j = 0; j < 4; ++j) {
    li[j][j] = make_float2(idg[j], 0.f);
    for (int r = j+1; r < 4; ++r) {
      float2 s = make_float2(0.f, 0.f);
      for (int d = j; d < r; ++d) s = cadd(s, cmul(a[r][d], li[d][j]));
      li[r][j] = make_float2(-s.x*idg[r], -s.y*idg[r]);
    }
  }
  for (int p = 0; p < 4; ++p)
    for (int q = 0; q < 4; ++q) {
      float2 s = make_float2(0.f, 0.f);
      for (int d = (p > q ? p : q); d < 4; ++d)
        s = cadd(s, cmulc(li[d][q], li[d][p]));
      out[p][q] = s;
    }
}

// 512 threads (8 waves/CU = 2/SIMD for latency hiding; grid is pinned at 256 = CU count).
// Thread (tm=t>>4 in 0..31, tp=t&15): A rows 4tm..4tm+3 x cols 8tp..8tp+7 (64 VGPRs);
// B rows 4tm..4tm+3 x cols tp+16q, q=0..7 (64 VGPRs). No dynamic register indexing.
__global__ __launch_bounds__(512, 2) void k_fused(
    const float* __restrict__ v_re, const float* __restrict__ v_im,
    const float* __restrict__ H_re, const float* __restrict__ H_im,
    const float* __restrict__ noise_pow, const float* __restrict__ rweights,
    const float* __restrict__ bss_pow, const int* __restrict__ assign_g,
    void* __restrict__ outp, int omode)
{
  const int t = threadIdx.x;
  const int lane = t & 63, wid = t >> 6;
  const int blk = blockIdx.x;
  const int b = blk >> 3, c = blk & 7;
  const int tm = t >> 4, tp = t & 15;
  const int rbase = tm * 4, cbase = tp * 8;

  // Arena reused over time: phaseA (Vs|Tb|covS|HdVS) -> ul (Hs|Ys) ->
  // Householder/back-transform partials Pd (32x130, padded) -> bisection Bs (128x32)
  __shared__ __align__(16) float2 Arena[4160];
  __shared__ __align__(16) float2 pS[1024];     // Wall (512) | uwS (512)
  __shared__ __align__(16) float2 dBS2[256];    // B-dot reduce, 2 halves
  __shared__ __align__(16) float2 vS[128];      // back-transform only
  __shared__ __align__(16) float2 wS[160];      // skewed (SK)
  __shared__ __align__(16) float2 colS[160];    // skewed (SK)
  __shared__ __align__(16) float2 pvS[128];
  __shared__ __align__(16) float2 tauS[128];
  __shared__ float dS[128], eS[128], cpS[128];
  __shared__ float red[8];
  __shared__ int asg[K_], ulist[K_], nc_s;

  float2* Wall = pS;
  float2* uwS  = pS + 512;
  float2* Vs   = Arena;           // 772 used (skewed stride-6 + per-32-block pad)
  float2* Tb   = Arena + 776;     // 512
  float2* covS = Arena + 1288;    // 512
  float2* HdVS = Arena + 1800;    // 512
  float2* Hs   = Arena;           // 4 x 130
  float2* Ys   = Arena + 520;     // 4 x 160 (octet-skewed)
  float2* Pd   = Arena;           // 32 x 130 partials
  float2* Bs   = Arena;           // 128 x 32 bisection

  if (t < K_) asg[t] = assign_g[t];
  if (t == 0) {
    int n2 = 0;
    for (int k = 0; k < K_; ++k) if (assign_g[k] == c) ulist[n2++] = k;
    nc_s = n2;
  }
  {
    const int k = t >> 4, n = (t >> 2) & 3, q = t & 3;
    covS[t] = make_float2((n == q) ? noise_pow[b*K_ + k] : 0.f, 0.f);
  }
  __syncthreads();
  const int nc = nc_s;
  if (nc == 0) return;
  const int cols = 4 * nc;
  const int qmax = (cols + 15) >> 4;
  const int passes = (cols + 31) >> 5;

  // ============ phase A: T_{jk} = H[asg_j,k] @ V_j ; cov_k += T T^H ============
  {
    const int pn = t >> 2;           // (k,n): kk = pn>>2, nn = pn&3
    const int qt = t & 3;            // m quarter
    const int kk = pn >> 2, nn = pn & 3;
    const float2* Vq = Vs + qt*2;    // per-quarter skew base
    for (int j = 0; j < K_; ++j) {
      const int vb = (b*K_ + j) * 512;
      Vs[(t >> 2)*6 + (t & 3) + (t >> 7)*2] = make_float2(v_re[vb + t], v_im[vb + t]);
      __syncthreads();
      const int hb = ((asg[j]*K_ + kk)*4 + nn) * 128;
      float2 a0 = {0,0}, a1 = {0,0}, a2 = {0,0}, a3 = {0,0};
      for (int m4 = qt*32; m4 < qt*32 + 32; m4 += 4) {
        const float4 hre = *(const float4*)&H_re[hb + m4];
        const float4 him = *(const float4*)&H_im[hb + m4];
        const float hx[4] = {hre.x, hre.y, hre.z, hre.w};
        const float hy[4] = {him.x, him.y, him.z, him.w};
        #pragma unroll
        for (int i = 0; i < 4; ++i) {
          const float4 v01 = *(const float4*)&Vq[(m4 + i)*6];
          const float4 v23 = *(const float4*)&Vq[(m4 + i)*6 + 2];
          a0.x += hx[i]*v01.x - hy[i]*v01.y; a0.y += hx[i]*v01.y + hy[i]*v01.x;
          a1.x += hx[i]*v01.z - hy[i]*v01.w; a1.y += hx[i]*v01.w + hy[i]*v01.z;
          a2.x += hx[i]*v23.x - hy[i]*v23.y; a2.y += hx[i]*v23.y + hy[i]*v23.x;
          a3.x += hx[i]*v23.z - hy[i]*v23.w; a3.y += hx[i]*v23.w + hy[i]*v23.z;
        }
      }
      #pragma unroll
      for (int o = 1; o <= 2; o <<= 1) {
        a0.x += __shfl_xor(a0.x, o, 64); a0.y += __shfl_xor(a0.y, o, 64);
        a1.x += __shfl_xor(a1.x, o, 64); a1.y += __shfl_xor(a1.y, o, 64);
        a2.x += __shfl_xor(a2.x, o, 64); a2.y += __shfl_xor(a2.y, o, 64);
        a3.x += __shfl_xor(a3.x, o, 64); a3.y += __shfl_xor(a3.y, o, 64);
      }
      if (qt == 0) {
        Tb[pn*4 + 0] = a0; Tb[pn*4 + 1] = a1; Tb[pn*4 + 2] = a2; Tb[pn*4 + 3] = a3;
      }
      __syncthreads();
      {
        const int k2 = t >> 4, n2 = (t >> 2) & 3, q2 = t & 3;
        float2 acc = covS[t];
        #pragma unroll
        for (int p = 0; p < 4; ++p)
          acc = cadd(acc, cmulc(Tb[(k2*4 + n2)*4 + p], Tb[(k2*4 + q2)*4 + p]));
        covS[t] = acc;
        if (k2 == j) HdVS[k2*16 + n2*4 + q2] = Tb[(k2*4 + n2)*4 + q2];
      }
      __syncthreads();
    }
  }

  // ============ phase B: per-user 4x4 chain -> uwS, Wall ============
  if (t < K_) {
    const int k = t;
    float2 a[4][4], ic[4][4], hv[4][4], u[4][4], wi[4][4], w[4][4], uw[4][4], W[4][4];
    const float rwk = rweights[b*K_ + k];
    for (int r = 0; r < 4; ++r)
      for (int c2 = 0; c2 < 4; ++c2) a[r][c2] = covS[k*16 + r*4 + c2];
    herm4_inv(a, ic);
    for (int r = 0; r < 4; ++r)
      for (int c2 = 0; c2 < 4; ++c2) hv[r][c2] = HdVS[k*16 + r*4 + c2];
    for (int n = 0; n < 4; ++n)
      for (int p = 0; p < 4; ++p) {
        float2 s = {0,0};
        for (int q = 0; q < 4; ++q) s = cadd(s, cmul(ic[n][q], hv[q][p]));
        u[n][p] = s;
      }
    for (int n = 0; n < 4; ++n)
      for (int p = 0; p < 4; ++p) {
        float2 s = make_float2((n == p) ? 1.f : 0.f, 0.f);
        for (int q = 0; q < 4; ++q) s = csub(s, cmulc(hv[q][p], u[q][n]));
        wi[n][p] = s;
      }
    herm4_inv(wi, w);
    for (int n = 0; n < 4; ++n)
      for (int q = 0; q < 4; ++q) {
        float2 s = {0,0};
        for (int p = 0; p < 4; ++p) s = cadd(s, cmul(u[n][p], w[p][q]));
        uw[n][q] = s;
      }
    for (int n = 0; n < 4; ++n)
      for (int r = 0; r < 4; ++r) {
        float2 s = {0,0};
        for (int q = 0; q < 4; ++q) s = cadd(s, cmulc(uw[n][q], u[r][q]));
        W[n][r] = make_float2(s.x * rwk, s.y * rwk);
      }
    for (int n = 0; n < 4; ++n)
      for (int r = n; r < 4; ++r) {
        float2 x1 = W[n][r], x2 = W[r][n];
        float2 hm = make_float2(0.5f*(x1.x + x2.x), 0.5f*(x1.y - x2.y));
        W[n][r] = hm; W[r][n] = make_float2(hm.x, -hm.y);
      }
    for (int idx = 0; idx < 16; ++idx) {
      uwS[k*16 + idx]  = uw[idx >> 2][idx & 3];
      Wall[k*16 + idx] = W[idx >> 2][idx & 3];
    }
  }
  __syncthreads();

  // ============ vt -> B registers (col tp+16q); bracket hi ============
  float2 Bv[4][8];
  #pragma unroll
  for (int j = 0; j < 4; ++j)
    #pragma unroll
    for (int q = 0; q < 8; ++q) Bv[j][q] = make_float2(0.f, 0.f);
  float trp = 0.f;
  #pragma unroll
  for (int q = 0; q < 8; ++q) {
    const int col = tp + 16*q;
    const int slot = col >> 2, qn = col & 3;
    if (slot < nc) {
      const int k = ulist[slot];
      const float rwk = rweights[b*K_ + k];
      const int hb = (c*K_ + k) * 512;
      float2 acc0 = {0,0}, acc1 = {0,0}, acc2 = {0,0}, acc3 = {0,0};
      #pragma unroll
      for (int n = 0; n < 4; ++n) {
        const float2 uwv = uwS[k*16 + n*4 + qn];
        const float4 hre = *(const float4*)&H_re[hb + n*128 + rbase];
        const float4 him = *(const float4*)&H_im[hb + n*128 + rbase];
        acc0 = cadd(acc0, cmulc(uwv, make_float2(hre.x, him.x)));
        acc1 = cadd(acc1, cmulc(uwv, make_float2(hre.y, him.y)));
        acc2 = cadd(acc2, cmulc(uwv, make_float2(hre.z, him.z)));
        acc3 = cadd(acc3, cmulc(uwv, make_float2(hre.w, him.w)));
      }
      acc0.x *= rwk; acc0.y *= rwk; acc1.x *= rwk; acc1.y *= rwk;
      acc2.x *= rwk; acc2.y *= rwk; acc3.x *= rwk; acc3.y *= rwk;
      Bv[0][q] = acc0; Bv[1][q] = acc1; Bv[2][q] = acc2; Bv[3][q] = acc3;
      trp += acc0.x*acc0.x + acc0.y*acc0.y + acc1.x*acc1.x + acc1.y*acc1.y
           + acc2.x*acc2.x + acc2.y*acc2.y + acc3.x*acc3.x + acc3.y*acc3.y;
    }
  }
  #pragma unroll
  for (int o = 32; o >= 1; o >>= 1) trp += __shfl_xor(trp, o, 64);
  if (lane == 0) red[wid] = trp;
  __syncthreads();
  const float inv_bss = 1.f / bss_pow[b*C_ + c];
  float hi = sqrtf((red[0] + red[1] + red[2] + red[3] +
                    red[4] + red[5] + red[6] + red[7]) * inv_bss);
  float lo = 0.f;

  // ============ ul = sum_k H^H W_k H into A registers (4x8/thread) ============
  float2 Areg[4][8];
  #pragma unroll
  for (int j = 0; j < 4; ++j)
    #pragma unroll
    for (int cc = 0; cc < 8; ++cc) Areg[j][cc] = make_float2(0.f, 0.f);
  __syncthreads();
  for (int k = 0; k < K_; ++k) {
    const int hb = (c*K_ + k) * 512;
    Hs[(t >> 7)*130 + (t & 127)] = make_float2(H_re[hb + t], H_im[hb + t]);
    __syncthreads();
    {
      const int n = t >> 7, p = t & 127;
      float2 y = {0,0};
      #pragma unroll
      for (int o = 0; o < 4; ++o) y = cadd(y, cmul(Wall[k*16 + n*4 + o], Hs[o*130 + p]));
      Ys[n*160 + p + ((p >> 3) << 1)] = y;   // octet-skewed store
    }
    __syncthreads();
    #pragma unroll
    for (int n = 0; n < 4; ++n) {
      float2 h[4], y[8];
      {
        const float4 ha = *(const float4*)&Hs[n*130 + rbase];
        const float4 hc = *(const float4*)&Hs[n*130 + rbase + 2];
        h[0] = make_float2(ha.x, ha.y); h[1] = make_float2(ha.z, ha.w);
        h[2] = make_float2(hc.x, hc.y); h[3] = make_float2(hc.z, hc.w);
        const float2* yb = &Ys[n*160 + tp*10];   // = SK(cbase)
        #pragma unroll
        for (int a2 = 0; a2 < 8; a2 += 2) {
          const float4 y4 = *(const float4*)&yb[a2];
          y[a2] = make_float2(y4.x, y4.y); y[a2+1] = make_float2(y4.z, y4.w);
        }
      }
      #pragma unroll
      for (int j = 0; j < 4; ++j)
        #pragma unroll
        for (int cc = 0; cc < 8; ++cc) {   // A += conj(h)*y
          Areg[j][cc].x += h[j].x*y[cc].x + h[j].y*y[cc].y;
          Areg[j][cc].y += h[j].x*y[cc].y - h[j].y*y[cc].x;
        }
    }
    __syncthreads();
  }

  // ============ Householder tridiagonalization (127 steps, B fused) ============
  // 3 barriers/iter; reflector scalars computed redundantly per-wave from colS
  // (bitwise identical across waves), v fragments built in registers (no vS).
  if (tp == 0) {
    #pragma unroll
    for (int j = 0; j < 4; ++j) colS[SK(rbase + j)] = Areg[j][0];
  }
  __syncthreads();

  #pragma unroll 1
  for (int i = 0; i < 127; ++i) {
    float2 vr[4], vc[8], tau, sc;
    {
      const float2 x0 = colS[SK(lane)], x1 = colS[SK(lane + 64)];
      float sig = 0.f;
      if (lane >= i + 2)      sig += x0.x*x0.x + x0.y*x0.y;
      if (lane + 64 >= i + 2) sig += x1.x*x1.x + x1.y*x1.y;
      #pragma unroll
      for (int o = 32; o >= 1; o >>= 1) sig += __shfl_xor(sig, o, 64);
      const float2 al = colS[SK(i + 1)];
      float beta;
      if (sig <= 1e-30f && fabsf(al.y) <= 1e-30f) {
        beta = al.x; tau = make_float2(0.f, 0.f); sc = make_float2(0.f, 0.f);
      } else {
        const float mag = sqrtf(al.x*al.x + al.y*al.y + sig);
        beta = (al.x >= 0.f) ? -mag : mag;
        const float ib = 1.f / beta;
        tau = make_float2((beta - al.x) * ib, -al.y * ib);
        const float dx = al.x - beta, dy = al.y;
        const float dn = 1.f / (dx*dx + dy*dy);
        sc = make_float2(dx*dn, -dy*dn);
      }
      if (t == 0) { eS[i] = beta; tauS[i] = tau; }
      #pragma unroll
      for (int j = 0; j < 4; ++j) {
        const int r = rbase + j;
        const float2 x = colS[SK(r)];
        vr[j] = (r <= i) ? make_float2(0.f, 0.f)
              : (r == i + 1 ? make_float2(1.f, 0.f) : cmul(x, sc));
      }
      {
        const int cb = SK(cbase);
        const float4 c01 = *(const float4*)&colS[cb];
        const float4 c23 = *(const float4*)&colS[cb + 2];
        const float4 c45 = *(const float4*)&colS[cb + 4];
        const float4 c67 = *(const float4*)&colS[cb + 6];
        const float2 cx[8] = { make_float2(c01.x,c01.y), make_float2(c01.z,c01.w),
                               make_float2(c23.x,c23.y), make_float2(c23.z,c23.w),
                               make_float2(c45.x,c45.y), make_float2(c45.z,c45.w),
                               make_float2(c67.x,c67.y), make_float2(c67.z,c67.w) };
        #pragma unroll
        for (int cc = 0; cc < 8; ++cc) {
          const int r = cbase + cc;
          vc[cc] = (r <= i) ? make_float2(0.f, 0.f)
                 : (r == i + 1 ? make_float2(1.f, 0.f) : cmul(cx[cc], sc));
        }
      }
    }
    // matvec partials + B-dot partials
    {
      float2 part[4];
      #pragma unroll
      for (int j = 0; j < 4; ++j) {
        float2 s = cmul(Areg[j][0], vc[0]);
        #pragma unroll
        for (int cc = 1; cc < 8; ++cc) s = cadd(s, cmul(Areg[j][cc], vc[cc]));
        part[j] = s;
      }
      #pragma unroll
      for (int o = 1; o <= 8; o <<= 1) {
        #pragma unroll
        for (int j = 0; j < 4; ++j) {
          part[j].x += __shfl_xor(part[j].x, o, 64);
          part[j].y += __shfl_xor(part[j].y, o, 64);
        }
      }
      #pragma unroll
      for (int j = 0; j < 4; ++j) if (tp == j) pvS[rbase + j] = part[j];
      #pragma unroll
      for (int q = 0; q < 8; ++q) {
        if (q >= qmax) continue;
        float2 s = {0.f, 0.f};
        #pragma unroll
        for (int j = 0; j < 4; ++j) s = cadd(s, cmulc(Bv[j][q], vr[j]));  // conj(v)*B
        Pd[tm*130 + tp + 16*q] = s;
      }
    }
    __syncthreads();

    // wave0 builds w~ ; waves1-4 reduce B-dots (two half-sums per column)
    if (wid == 0) {
      float2 p0 = {0.f,0.f}, p1 = {0.f,0.f};
      if (lane > i)      p0 = cmul(tau, pvS[lane]);
      if (lane + 64 > i) p1 = cmul(tau, pvS[lane + 64]);
      float2 v0, v1;
      v0 = (lane <= i) ? make_float2(0.f,0.f)
         : (lane == i + 1 ? make_float2(1.f,0.f) : cmul(colS[SK(lane)], sc));
      { const int r1 = lane + 64;
        v1 = (r1 <= i) ? make_float2(0.f,0.f)
           : (r1 == i + 1 ? make_float2(1.f,0.f) : cmul(colS[SK(r1)], sc)); }
      float2 d0 = cadd(cmulc(p0, v0), cmulc(p1, v1));
      #pragma unroll
      for (int o = 32; o >= 1; o >>= 1) {
        d0.x += __shfl_xor(d0.x, o, 64);
        d0.y += __shfl_xor(d0.y, o, 64);
      }
      const float alr = -0.5f * (tau.x*d0.x + tau.y*d0.y);
      wS[SK(lane)]      = cadd(p0, make_float2(alr*v0.x, alr*v0.y));
      wS[SK(lane + 64)] = cadd(p1, make_float2(alr*v1.x, alr*v1.y));
    } else if (t < 320) {
      const int col = (t - 64) & 127;
      const int half = (t - 64) >> 7;
      float2 s = {0.f, 0.f};
      #pragma unroll
      for (int g = 0; g < 16; ++g) s = cadd(s, Pd[(half*16 + g)*130 + col]);
      dBS2[half*128 + col] = s;
    }
    __syncthreads();

    // rank-2 update + B update + store v col i + extract col i+1
    {
      float2 wr[4], wc[8];
      #pragma unroll
      for (int j = 0; j < 4; ++j) wr[j] = wS[SK(rbase + j)];
      {
        const int cb = SK(cbase);
        const float4 w01 = *(const float4*)&wS[cb];
        const float4 w23 = *(const float4*)&wS[cb + 2];
        const float4 w45 = *(const float4*)&wS[cb + 4];
        const float4 w67 = *(const float4*)&wS[cb + 6];
        wc[0] = make_float2(w01.x,w01.y); wc[1] = make_float2(w01.z,w01.w);
        wc[2] = make_float2(w23.x,w23.y); wc[3] = make_float2(w23.z,w23.w);
        wc[4] = make_float2(w45.x,w45.y); wc[5] = make_float2(w45.z,w45.w);
        wc[6] = make_float2(w67.x,w67.y); wc[7] = make_float2(w67.z,w67.w);
      }
      #pragma unroll
      for (int j = 0; j < 4; ++j)
        #pragma unroll
        for (int cc = 0; cc < 8; ++cc)   // A[r][c] -= v[r]*conj(w[c]) + w[r]*conj(v[c])
          Areg[j][cc] = csub(Areg[j][cc], cadd(cmulc(vr[j], wc[cc]), cmulc(wr[j], vc[cc])));
      const float2 tauc = make_float2(tau.x, -tau.y);
      #pragma unroll
      for (int q = 0; q < 8; ++q) {
        if (q >= qmax) continue;
        const float2 dBt = cmul(tauc, cadd(dBS2[tp + 16*q], dBS2[128 + tp + 16*q]));
        #pragma unroll
        for (int j = 0; j < 4; ++j) Bv[j][q] = csub(Bv[j][q], cmul(dBt, vr[j]));
      }
      if (tp == (i >> 3)) {
        #pragma unroll
        for (int cc = 0; cc < 8; ++cc) if (cc == (i & 7)) {
          #pragma unroll
          for (int j = 0; j < 4; ++j) if (rbase + j >= i + 1) Areg[j][cc] = vr[j];
        }
      }
      if (tp == ((i + 1) >> 3)) {
        #pragma unroll
        for (int cc = 0; cc < 8; ++cc) if (cc == ((i + 1) & 7)) {
          #pragma unroll
          for (int j = 0; j < 4; ++j) colS[SK(rbase + j)] = Areg[j][cc];
        }
      }
    }
    __syncthreads();
  }

  // diag of T (row rbase+j lives in col-owner tp == tm>>1)
  if (tp == (tm >> 1)) {
    const int co = (tm & 1) * 4;
    #pragma unroll
    for (int j = 0; j < 4; ++j)
      #pragma unroll
      for (int cc = 0; cc < 8; ++cc)
        if (cc == co + j) dS[rbase + j] = Areg[j][cc].x;
  }
  __syncthreads();

  // ============ bisection: 8 iters + final solve (Thomas, wave0) ============
  for (int it = 0; it <= 8; ++it) {
    const float mu = 0.5f * (lo + hi);
    float fsum = 0.f;
    #pragma unroll
    for (int p = 0; p < 4; ++p) {
      if (p >= passes) continue;
      __syncthreads();
      #pragma unroll
      for (int j = 0; j < 4; ++j) {
        Bs[(rbase + j)*32 + tp]      = Bv[j][2*p];
        Bs[(rbase + j)*32 + tp + 16] = Bv[j][2*p + 1];
      }
      __syncthreads();
      if (wid == 0) {
        const int colg = 32*p + lane;
        const bool act = (lane < 32) && (colg < cols);
        float m = dS[0] + mu;
        float im = 1.f / m;
        float2 g = act ? Bs[lane] : make_float2(0.f, 0.f);
        g.x *= im; g.y *= im;
        if (act) Bs[lane] = g;
        float cp = eS[0] * im;
        if (lane == 0) cpS[0] = cp;
        for (int r = 1; r < 128; ++r) {
          const float e0 = eS[r-1];
          m = dS[r] + mu - e0 * cp;
          im = 1.f / m;
          float2 gr = act ? Bs[r*32 + lane] : make_float2(0.f, 0.f);
          gr.x = (gr.x - e0 * g.x) * im;
          gr.y = (gr.y - e0 * g.y) * im;
          g = gr;
          if (act) Bs[r*32 + lane] = gr;
          if (r < 127) { cp = eS[r] * im; if (lane == 0) cpS[r] = cp; }
        }
        float2 z = g;
        float acc = z.x*z.x + z.y*z.y;
        for (int r = 126; r >= 0; --r) {
          const float cpr = cpS[r];
          const float2 gp = act ? Bs[r*32 + lane] : make_float2(0.f, 0.f);
          z.x = gp.x - cpr * z.x;
          z.y = gp.y - cpr * z.y;
          acc += z.x*z.x + z.y*z.y;
          if (it == 8 && act) Bs[r*32 + lane] = z;
        }
        if (act) fsum += acc;
      }
      if (it == 8) {
        __syncthreads();
        #pragma unroll
        for (int j = 0; j < 4; ++j) {
          Bv[j][2*p]     = Bs[(rbase + j)*32 + tp];
          Bv[j][2*p + 1] = Bs[(rbase + j)*32 + tp + 16];
        }
      }
    }
    if (it < 8 && wid == 0) {
      #pragma unroll
      for (int o = 32; o >= 1; o >>= 1) fsum += __shfl_xor(fsum, o, 64);
      const float f = fsum * inv_bss;
      if (f > 1.0f) lo = mu; else hi = mu;   // only wave0's lo/hi are consumed
    }
  }
  __syncthreads();

  // ============ back-transform y = Q z (reverse reflector replay, 3 barriers) ============
  #pragma unroll 1
  for (int i = 126; i >= 0; --i) {
    if (t < 128 && t <= i) vS[t] = make_float2(0.f, 0.f);
    if (tp == (i >> 3)) {
      #pragma unroll
      for (int cc = 0; cc < 8; ++cc) if (cc == (i & 7)) {
        #pragma unroll
        for (int j = 0; j < 4; ++j) if (rbase + j >= i + 1) vS[rbase + j] = Areg[j][cc];
      }
    }
    __syncthreads();
    float2 vr[4];
    #pragma unroll
    for (int j = 0; j < 4; ++j) vr[j] = vS[rbase + j];
    #pragma unroll
    for (int q = 0; q < 8; ++q) {
      if (q >= qmax) continue;
      float2 s = {0.f, 0.f};
      #pragma unroll
      for (int j = 0; j < 4; ++j) s = cadd(s, cmulc(Bv[j][q], vr[j]));
      Pd[tm*130 + tp + 16*q] = s;
    }
    __syncthreads();
    if (t < 256) {
      const int col = t & 127;
      const int half = t >> 7;
      float2 s = {0.f, 0.f};
      #pragma unroll
      for (int g = 0; g < 16; ++g) s = cadd(s, Pd[(half*16 + g)*130 + col]);
      dBS2[half*128 + col] = s;
    }
    __syncthreads();
    {
      const float2 tau2 = tauS[i];
      #pragma unroll
      for (int q = 0; q < 8; ++q) {
        if (q >= qmax) continue;
        const float2 dBt = cmul(tau2, cadd(dBS2[tp + 16*q], dBS2[128 + tp + 16*q]));
        #pragma unroll
        for (int j = 0; j < 4; ++j) Bv[j][q] = csub(Bv[j][q], cmul(dBt, vr[j]));
      }
    }
    // no trailing barrier needed: next iter's vS writes are fenced by the
    // reduce barrier above (all vr reads of this iter completed before it)
  }

  // ============ output ============
  #pragma unroll
  for (int q = 0; q < 8; ++q) {
    const int col = tp + 16*q;
    const int slot = col >> 2, qn = col & 3;
    if (slot < nc) {
      const int k = ulist[slot];
      const size_t base = (size_t)(b*K_ + k) * 512;
      #pragma unroll
      for (int j = 0; j < 4; ++j) {
        const size_t oe = base + (size_t)(rbase + j)*4 + qn;
        if (omode == 0) ((float2*)outp)[oe] = Bv[j][q];
        else            ((float*)outp)[oe]  = Bv[j][q].x;
      }
    }
  }
}

// ======================================================================================
extern "C" void kernel_launch(void* const* d_in, const int* in_sizes, int n_in,
                              void* d_out, int out_size, void* d_ws, size_t ws_size,
                              hipStream_t stream)
{
  (void)in_sizes; (void)n_in; (void)d_ws; (void)ws_size;
  const float* v_re   = (const float*)d_in[0];
  const float* v_im   = (const float*)d_in[1];
  const float* H_re   = (const float*)d_in[2];
  const float* H_im   = (const float*)d_in[3];
  const float* noise  = (const float*)d_in[4];
  const float* rw     = (const float*)d_in[5];
  const float* bss    = (const float*)d_in[6];
  const int*   assign = (const int*)d_in[7];

  const int omode = (out_size == B_*K_*128*4) ? 1 : 0;  // real-only vs interleaved complex

  hipLaunchKernelGGL(k_fused, dim3(B_*C_), dim3(512), 0, stream,
                     v_re, v_im, H_re, H_im, noise, rw, bss, assign, d_out, omode);
}